// Round 5
// baseline (248.738 us; speedup 1.0000x reference)
//
#include <hip/hip_runtime.h>
#include <hip/hip_bf16.h>

#define BB 8
#define NN 1024
#define FIN 256
#define FOUT 64
#define NEGV (-9000000000000000.0f)

typedef __hip_bfloat16 bf16;
typedef short bf16x8 __attribute__((ext_vector_type(8)));
typedef float f32x4 __attribute__((ext_vector_type(4)));

__device__ __forceinline__ float b2f(bf16 v) { return __bfloat162float(v); }
__device__ __forceinline__ float bu2f(unsigned short u) {
  union { unsigned int i; float f; } c;
  c.i = ((unsigned int)u) << 16;
  return c.f;
}
__device__ __forceinline__ unsigned short f2bu(float v) {
  bf16 t = __float2bfloat16(v);
  return *(unsigned short*)&t;
}

// async global->LDS, 16B per lane; LDS dest is wave-uniform base (+lane*16 by HW)
__device__ __forceinline__ void gload_lds16(const unsigned short* g,
                                            unsigned short* l) {
  __builtin_amdgcn_global_load_lds(
      (__attribute__((address_space(1))) void*)(unsigned long long)(const void*)g,
      (__attribute__((address_space(3))) void*)l, 16, 0, 0);
}

__device__ __forceinline__ float waveRedSum(float v) {
  for (int d = 32; d; d >>= 1) v += __shfl_down(v, d);
  return v;
}
__device__ __forceinline__ float waveRedMax(float v) {
  for (int d = 32; d; d >>= 1) v = fmaxf(v, __shfl_down(v, d));
  return v;
}
__device__ __forceinline__ float waveRedMin(float v) {
  for (int d = 32; d; d >>= 1) v = fminf(v, __shfl_down(v, d));
  return v;
}

__device__ __forceinline__ float blockSumF(float v, float* tmp) {
  __syncthreads();
  v = waveRedSum(v);
  if ((threadIdx.x & 63) == 0) tmp[threadIdx.x >> 6] = v;
  __syncthreads();
  return tmp[0] + tmp[1] + tmp[2] + tmp[3];
}
__device__ __forceinline__ float blockMaxF(float v, float* tmp) {
  __syncthreads();
  v = waveRedMax(v);
  if ((threadIdx.x & 63) == 0) tmp[threadIdx.x >> 6] = v;
  __syncthreads();
  return fmaxf(fmaxf(tmp[0], tmp[1]), fmaxf(tmp[2], tmp[3]));
}
__device__ __forceinline__ float blockMinF(float v, float* tmp) {
  __syncthreads();
  v = waveRedMin(v);
  if ((threadIdx.x & 63) == 0) tmp[threadIdx.x >> 6] = v;
  __syncthreads();
  return fminf(fminf(tmp[0], tmp[1]), fminf(tmp[2], tmp[3]));
}

__global__ void k_fill(unsigned short* o, int n, unsigned short pat) {
  int i = blockIdx.x * blockDim.x + threadIdx.x;
  int stride = gridDim.x * blockDim.x;
  for (; i < n; i += stride) o[i] = pat;
}

__global__ void k_zero(float* p, int n) {
  int i = blockIdx.x * blockDim.x + threadIdx.x;
  if (i < n) p[i] = 0.f;
}

// dtype probe
__global__ void k_detect(const unsigned short* xu, float* flag) {
  const int tid = threadIdx.x;
  float mx = 0.0f, zc = 0.0f;
  for (int i = tid; i < 8192; i += 256) {
    unsigned short u = xu[i];
    float v = bu2f(u);
    if (u == 0 || u == 0x8000) zc += 1.0f;
    mx = fmaxf(mx, fabsf(v));
  }
  __shared__ float tmp[4];
  float gm = blockMaxF(mx, tmp);
  float gz = blockSumF(zc, tmp);
  if (tid == 0) flag[0] = (gm > 1.0e6f || gz > 2048.0f) ? 1.0f : 0.0f;
}

// h = x @ W per (b,n) row, emitted as split bf16 (hi/lo); sq = |h|^2 (exact f32);
// wh1 = h.a1; wh2 = h.a2
__global__ void __launch_bounds__(64) k_h(const void* xv, const void* Wv,
                                          const void* av,
                                          const float* __restrict__ flag,
                                          unsigned short* __restrict__ Hh,
                                          unsigned short* __restrict__ Hl,
                                          float* __restrict__ sq,
                                          float* __restrict__ wh1,
                                          float* __restrict__ wh2) {
  const int bn = blockIdx.x;
  const int o = threadIdx.x;
  const bool f32m = (flag[0] != 0.0f);
  __shared__ float xs[FIN];
  if (f32m) {
    const float* xr = (const float*)xv + (size_t)bn * FIN;
    for (int i = o; i < FIN; i += 64) xs[i] = xr[i];
  } else {
    const bf16* xr = (const bf16*)xv + (size_t)bn * FIN;
    for (int i = o; i < FIN; i += 64) xs[i] = b2f(xr[i]);
  }
  __syncthreads();
  float acc = 0.f;
  if (f32m) {
    const float* Wf = (const float*)Wv;
    for (int i = 0; i < FIN; ++i) acc += xs[i] * Wf[i * FOUT + o];
  } else {
    const bf16* Wb = (const bf16*)Wv;
    for (int i = 0; i < FIN; ++i) acc += xs[i] * b2f(Wb[i * FOUT + o]);
  }
  unsigned short hh = f2bu(acc);
  unsigned short hl = f2bu(acc - bu2f(hh));
  Hh[(size_t)bn * FOUT + o] = hh;
  Hl[(size_t)bn * FOUT + o] = hl;
  float a1, a2;
  if (f32m) {
    a1 = ((const float*)av)[o];
    a2 = ((const float*)av)[FOUT + o];
  } else {
    a1 = b2f(((const bf16*)av)[o]);
    a2 = b2f(((const bf16*)av)[FOUT + o]);
  }
  float s = waveRedSum(acc * acc);
  float w1 = waveRedSum(acc * a1);
  float w2 = waveRedSum(acc * a2);
  if (o == 0) {
    sq[bn] = s;
    wh1[bn] = w1;
    wh2[bn] = w2;
  }
}

// Pass 1: rowsums of M = exp(-dist) via MFMA (no stores). Proven k_g structure.
__global__ void __launch_bounds__(256) k_g0(const unsigned short* __restrict__ Hhp,
                                            const unsigned short* __restrict__ Hlp,
                                            const float* __restrict__ sq,
                                            float* __restrict__ rsum) {
  const int bid = blockIdx.x;
  const int z = bid & 7;
  const int t6 = bid >> 3;
  const int tr = (t6 >> 3) * 128, tc = (t6 & 7) * 128;
  const float* sqb = sq + (z << 10);
  float* rsb = rsum + (z << 10);
  __shared__ unsigned short sm[32768];
  const int tid = threadIdx.x;
  const int wave = tid >> 6, lane = tid & 63;
  const int wm = (wave >> 1) * 64, wn = (wave & 1) * 64;
  const int q = lane >> 4, ln = lane & 15;
  const int rl = lane >> 3;
  const int gcol = ((lane & 7) ^ rl) << 3;
  const size_t HB = (size_t)z * NN * FOUT;
  const unsigned short* gp0;
  unsigned short* lb;
  if (wave == 0)      { gp0 = Hhp + HB + (size_t)tr * FOUT; lb = sm; }
  else if (wave == 1) { gp0 = Hlp + HB + (size_t)tr * FOUT; lb = sm + 8192; }
  else if (wave == 2) { gp0 = Hhp + HB + (size_t)tc * FOUT; lb = sm + 16384; }
  else                { gp0 = Hlp + HB + (size_t)tc * FOUT; lb = sm + 24576; }
  for (int t = 0; t < 16; ++t)
    gload_lds16(gp0 + (size_t)(t * 8 + rl) * FOUT + gcol, lb + t * 512);
  f32x4 acc[4][4];
  for (int i = 0; i < 4; ++i)
    for (int j = 0; j < 4; ++j) acc[i][j] = (f32x4){0.f, 0.f, 0.f, 0.f};
  __syncthreads();
  const int swz = (ln & 7);
  for (int ks = 0; ks < 2; ++ks) {
    const int gq = ((ks * 4 + q) ^ swz) << 3;
    bf16x8 fah[4], fal[4], fbh[4], fbl[4];
    for (int i = 0; i < 4; ++i) {
      int off = (wm + i * 16 + ln) * 64 + gq;
      fah[i] = *(const bf16x8*)&sm[off];
      fal[i] = *(const bf16x8*)&sm[8192 + off];
    }
    for (int j = 0; j < 4; ++j) {
      int off = (wn + j * 16 + ln) * 64 + gq;
      fbh[j] = *(const bf16x8*)&sm[16384 + off];
      fbl[j] = *(const bf16x8*)&sm[24576 + off];
    }
    for (int i = 0; i < 4; ++i)
      for (int j = 0; j < 4; ++j) {
        acc[i][j] = __builtin_amdgcn_mfma_f32_16x16x32_bf16(fah[i], fbh[j], acc[i][j], 0, 0, 0);
        acc[i][j] = __builtin_amdgcn_mfma_f32_16x16x32_bf16(fah[i], fbl[j], acc[i][j], 0, 0, 0);
        acc[i][j] = __builtin_amdgcn_mfma_f32_16x16x32_bf16(fal[i], fbh[j], acc[i][j], 0, 0, 0);
      }
  }
  float rs[4] = {0.f, 0.f, 0.f, 0.f};
  for (int i = 0; i < 4; ++i) {
    int m0 = tr + wm + i * 16 + q * 4;
    float sm0[4];
    for (int reg = 0; reg < 4; ++reg) sm0[reg] = sqb[m0 + reg];
    for (int j = 0; j < 4; ++j) {
      int n = tc + wn + j * 16 + ln;
      float sn = sqb[n];
      for (int reg = 0; reg < 4; ++reg) {
        int m = m0 + reg;
        float d2 = sm0[reg] + sn - 2.0f * acc[i][j][reg];
        float v = (m == n) ? 1.0f : ((d2 > 0.0f) ? expf(-sqrtf(d2)) : 1.0f);
        rs[j] += v;
      }
    }
  }
  for (int j = 0; j < 4; ++j) {
    float v = rs[j];
    v += __shfl_xor(v, 16);
    v += __shfl_xor(v, 32);
    if (q == 0) {
      int n = tc + wn + j * 16 + ln;
      atomicAdd(&rsb[n], v);
    }
  }
}

// dcl[i] = max(rsum,1e-12); isq[i] = 1/sqrt(dcl)
__global__ void __launch_bounds__(256) k_scal(const float* __restrict__ rsum,
                                              float* __restrict__ dcl,
                                              float* __restrict__ isq) {
  int i = blockIdx.x * blockDim.x + threadIdx.x;
  if (i < BB * NN) {
    float r = fmaxf(rsum[i], 1e-12f);
    dcl[i] = r;
    isq[i] = 1.0f / sqrtf(r);
  }
}

// Pass 2: W = D^-1/2 M D^-1/2 via MFMA recompute, split bf16 store.
__global__ void __launch_bounds__(256) k_gw(const unsigned short* __restrict__ Hhp,
                                            const unsigned short* __restrict__ Hlp,
                                            const float* __restrict__ sq,
                                            const float* __restrict__ isq,
                                            unsigned short* __restrict__ Wh,
                                            unsigned short* __restrict__ Wl) {
  const int bid = blockIdx.x;
  const int z = bid & 7;
  const int t6 = bid >> 3;
  const int tr = (t6 >> 3) * 128, tc = (t6 & 7) * 128;
  const size_t MAT = (size_t)NN * NN;
  const float* sqb = sq + (z << 10);
  const float* isqb = isq + (z << 10);
  unsigned short* whb = Wh + z * MAT;
  unsigned short* wlb = Wl + z * MAT;
  __shared__ unsigned short sm[32768];
  const int tid = threadIdx.x;
  const int wave = tid >> 6, lane = tid & 63;
  const int wm = (wave >> 1) * 64, wn = (wave & 1) * 64;
  const int q = lane >> 4, ln = lane & 15;
  const int rl = lane >> 3;
  const int gcol = ((lane & 7) ^ rl) << 3;
  const size_t HB = (size_t)z * NN * FOUT;
  const unsigned short* gp0;
  unsigned short* lb;
  if (wave == 0)      { gp0 = Hhp + HB + (size_t)tr * FOUT; lb = sm; }
  else if (wave == 1) { gp0 = Hlp + HB + (size_t)tr * FOUT; lb = sm + 8192; }
  else if (wave == 2) { gp0 = Hhp + HB + (size_t)tc * FOUT; lb = sm + 16384; }
  else                { gp0 = Hlp + HB + (size_t)tc * FOUT; lb = sm + 24576; }
  for (int t = 0; t < 16; ++t)
    gload_lds16(gp0 + (size_t)(t * 8 + rl) * FOUT + gcol, lb + t * 512);
  f32x4 acc[4][4];
  for (int i = 0; i < 4; ++i)
    for (int j = 0; j < 4; ++j) acc[i][j] = (f32x4){0.f, 0.f, 0.f, 0.f};
  __syncthreads();
  const int swz = (ln & 7);
  for (int ks = 0; ks < 2; ++ks) {
    const int gq = ((ks * 4 + q) ^ swz) << 3;
    bf16x8 fah[4], fal[4], fbh[4], fbl[4];
    for (int i = 0; i < 4; ++i) {
      int off = (wm + i * 16 + ln) * 64 + gq;
      fah[i] = *(const bf16x8*)&sm[off];
      fal[i] = *(const bf16x8*)&sm[8192 + off];
    }
    for (int j = 0; j < 4; ++j) {
      int off = (wn + j * 16 + ln) * 64 + gq;
      fbh[j] = *(const bf16x8*)&sm[16384 + off];
      fbl[j] = *(const bf16x8*)&sm[24576 + off];
    }
    for (int i = 0; i < 4; ++i)
      for (int j = 0; j < 4; ++j) {
        acc[i][j] = __builtin_amdgcn_mfma_f32_16x16x32_bf16(fah[i], fbh[j], acc[i][j], 0, 0, 0);
        acc[i][j] = __builtin_amdgcn_mfma_f32_16x16x32_bf16(fah[i], fbl[j], acc[i][j], 0, 0, 0);
        acc[i][j] = __builtin_amdgcn_mfma_f32_16x16x32_bf16(fal[i], fbh[j], acc[i][j], 0, 0, 0);
      }
  }
  for (int i = 0; i < 4; ++i) {
    int m0 = tr + wm + i * 16 + q * 4;
    float sm0[4], im[4];
    for (int reg = 0; reg < 4; ++reg) {
      sm0[reg] = sqb[m0 + reg];
      im[reg] = isqb[m0 + reg];
    }
    for (int j = 0; j < 4; ++j) {
      int n = tc + wn + j * 16 + ln;
      float sn = sqb[n];
      float isn = isqb[n];
      unsigned short hs[4], ls[4];
      for (int reg = 0; reg < 4; ++reg) {
        int m = m0 + reg;
        float d2 = sm0[reg] + sn - 2.0f * acc[i][j][reg];
        float v = (m == n) ? 1.0f : ((d2 > 0.0f) ? expf(-sqrtf(d2)) : 1.0f);
        float vw = v * im[reg] * isn;
        hs[reg] = f2bu(vw);
        ls[reg] = f2bu(vw - bu2f(hs[reg]));
      }
      ushort4 h4, l4;
      h4.x = hs[0]; h4.y = hs[1]; h4.z = hs[2]; h4.w = hs[3];
      l4.x = ls[0]; l4.y = ls[1]; l4.z = ls[2]; l4.w = ls[3];
      *(ushort4*)&whb[(size_t)n * NN + m0] = h4;
      *(ushort4*)&wlb[(size_t)n * NN + m0] = l4;
    }
  }
}

// MFMA GEMM1: U = W^2 (symmetric). 64x128 triangle tiles: ri(64-row) <= 2*cj+1.
// 72 pairs/z -> 576 blocks, 48KB LDS -> ~2-3 blocks/CU co-resident.
// Straight write is the unique canonical writer for its region; mirror writes
// only elements with no straight writer: guard (n>>6) > 2*(m0>>7)+1.
__global__ void __launch_bounds__(256) k_mm1(
    const unsigned short* __restrict__ Wh, const unsigned short* __restrict__ Wl,
    unsigned short* __restrict__ Uh, unsigned short* __restrict__ Ul) {
  const int bid = blockIdx.x;
  const int z = bid & 7;
  int p = bid >> 3;  // 0..71
  int cj = 0, rem = p;
  while (rem >= 2 * cj + 2) { rem -= 2 * cj + 2; ++cj; }
  const int ri = rem;  // 0..2cj+1
  const int r0 = ri * 64, c0 = cj * 128;
  const size_t MAT = (size_t)NN * NN;
  __shared__ unsigned short sm[24576];  // Ah 4096 | Al 4096 | Bh 8192 | Bl 8192
  const int tid = threadIdx.x;
  const int wave = tid >> 6, lane = tid & 63;
  const int wm = (wave >> 1) * 32, wn = (wave & 1) * 64;
  const int q = lane >> 4, ln = lane & 15;
  const int rl = lane >> 3;
  const int gcol = ((lane & 7) ^ rl) << 3;
  const unsigned short* gp0;
  unsigned short* lb;
  int nt;
  if (wave == 0)      { gp0 = Wh + z * MAT + (size_t)r0 * NN; lb = sm;         nt = 8; }
  else if (wave == 1) { gp0 = Wl + z * MAT + (size_t)r0 * NN; lb = sm + 4096;  nt = 8; }
  else if (wave == 2) { gp0 = Wh + z * MAT + (size_t)c0 * NN; lb = sm + 8192;  nt = 16; }
  else                { gp0 = Wl + z * MAT + (size_t)c0 * NN; lb = sm + 16384; nt = 16; }
  f32x4 acc[2][4];
  for (int i = 0; i < 2; ++i)
    for (int j = 0; j < 4; ++j) acc[i][j] = (f32x4){0.f, 0.f, 0.f, 0.f};
  const int swz = (ln & 7);
  for (int kc = 0; kc < NN; kc += 64) {
    __syncthreads();
    const unsigned short* gpk = gp0 + kc + gcol;
    for (int t = 0; t < nt; ++t)
      gload_lds16(gpk + (size_t)(t * 8 + rl) * NN, lb + t * 512);
    __syncthreads();
    for (int ks = 0; ks < 2; ++ks) {
      const int gq = ((ks * 4 + q) ^ swz) << 3;
      bf16x8 fah[2], fal[2], fbh[4], fbl[4];
      for (int i = 0; i < 2; ++i) {
        int off = (wm + i * 16 + ln) * 64 + gq;
        fah[i] = *(const bf16x8*)&sm[off];
        fal[i] = *(const bf16x8*)&sm[4096 + off];
      }
      for (int j = 0; j < 4; ++j) {
        int off = (wn + j * 16 + ln) * 64 + gq;
        fbh[j] = *(const bf16x8*)&sm[8192 + off];
        fbl[j] = *(const bf16x8*)&sm[16384 + off];
      }
      for (int i = 0; i < 2; ++i)
        for (int j = 0; j < 4; ++j) {
          acc[i][j] = __builtin_amdgcn_mfma_f32_16x16x32_bf16(fah[i], fbh[j], acc[i][j], 0, 0, 0);
          acc[i][j] = __builtin_amdgcn_mfma_f32_16x16x32_bf16(fah[i], fbl[j], acc[i][j], 0, 0, 0);
          acc[i][j] = __builtin_amdgcn_mfma_f32_16x16x32_bf16(fal[i], fbh[j], acc[i][j], 0, 0, 0);
        }
    }
  }
  unsigned short* cth = Uh + z * MAT;
  unsigned short* ctl = Ul + z * MAT;
  for (int i = 0; i < 2; ++i) {
    int m0 = r0 + wm + i * 16 + q * 4;
    for (int j = 0; j < 4; ++j) {
      int n = c0 + wn + j * 16 + ln;
      ushort4 h4, l4;
      unsigned short hs[4], ls[4];
      for (int reg = 0; reg < 4; ++reg) {
        float v = acc[i][j][reg];
        hs[reg] = f2bu(v);
        ls[reg] = f2bu(v - bu2f(hs[reg]));
      }
      h4.x = hs[0]; h4.y = hs[1]; h4.z = hs[2]; h4.w = hs[3];
      l4.x = ls[0]; l4.y = ls[1]; l4.z = ls[2]; l4.w = ls[3];
      *(ushort4*)&cth[(size_t)n * NN + m0] = h4;
      *(ushort4*)&ctl[(size_t)n * NN + m0] = l4;
      if ((n >> 6) > 2 * (m0 >> 7) + 1) {
        for (int reg = 0; reg < 4; ++reg) {
          cth[(size_t)(m0 + reg) * NN + n] = hs[reg];
          ctl[(size_t)(m0 + reg) * NN + n] = ls[reg];
        }
      }
    }
  }
}

// MFMA GEMM2: W^3 = U * W with FUSED combine:
// S[i][j] = 0.5*(d_i+d_j)*isq_i*isq_j*(W + 0.8U + 0.64*W^3)[i][j].
// Same 64x128 triangle geometry/dedup as k_mm1.
__global__ void __launch_bounds__(256) k_mm2(
    const unsigned short* __restrict__ Uh, const unsigned short* __restrict__ Ul,
    const unsigned short* __restrict__ Wh, const unsigned short* __restrict__ Wl,
    const float* __restrict__ dcl, const float* __restrict__ isq,
    float* __restrict__ S) {
  const int bid = blockIdx.x;
  const int z = bid & 7;
  int p = bid >> 3;
  int cj = 0, rem = p;
  while (rem >= 2 * cj + 2) { rem -= 2 * cj + 2; ++cj; }
  const int ri = rem;
  const int r0 = ri * 64, c0 = cj * 128;
  const size_t MAT = (size_t)NN * NN;
  __shared__ unsigned short sm[24576];
  const int tid = threadIdx.x;
  const int wave = tid >> 6, lane = tid & 63;
  const int wm = (wave >> 1) * 32, wn = (wave & 1) * 64;
  const int q = lane >> 4, ln = lane & 15;
  const int rl = lane >> 3;
  const int gcol = ((lane & 7) ^ rl) << 3;
  const unsigned short* gp0;
  unsigned short* lb;
  int nt;
  if (wave == 0)      { gp0 = Uh + z * MAT + (size_t)r0 * NN; lb = sm;         nt = 8; }
  else if (wave == 1) { gp0 = Ul + z * MAT + (size_t)r0 * NN; lb = sm + 4096;  nt = 8; }
  else if (wave == 2) { gp0 = Wh + z * MAT + (size_t)c0 * NN; lb = sm + 8192;  nt = 16; }
  else                { gp0 = Wl + z * MAT + (size_t)c0 * NN; lb = sm + 16384; nt = 16; }
  f32x4 acc[2][4];
  for (int i = 0; i < 2; ++i)
    for (int j = 0; j < 4; ++j) acc[i][j] = (f32x4){0.f, 0.f, 0.f, 0.f};
  const int swz = (ln & 7);
  for (int kc = 0; kc < NN; kc += 64) {
    __syncthreads();
    const unsigned short* gpk = gp0 + kc + gcol;
    for (int t = 0; t < nt; ++t)
      gload_lds16(gpk + (size_t)(t * 8 + rl) * NN, lb + t * 512);
    __syncthreads();
    for (int ks = 0; ks < 2; ++ks) {
      const int gq = ((ks * 4 + q) ^ swz) << 3;
      bf16x8 fah[2], fal[2], fbh[4], fbl[4];
      for (int i = 0; i < 2; ++i) {
        int off = (wm + i * 16 + ln) * 64 + gq;
        fah[i] = *(const bf16x8*)&sm[off];
        fal[i] = *(const bf16x8*)&sm[4096 + off];
      }
      for (int j = 0; j < 4; ++j) {
        int off = (wn + j * 16 + ln) * 64 + gq;
        fbh[j] = *(const bf16x8*)&sm[8192 + off];
        fbl[j] = *(const bf16x8*)&sm[16384 + off];
      }
      for (int i = 0; i < 2; ++i)
        for (int j = 0; j < 4; ++j) {
          acc[i][j] = __builtin_amdgcn_mfma_f32_16x16x32_bf16(fah[i], fbh[j], acc[i][j], 0, 0, 0);
          acc[i][j] = __builtin_amdgcn_mfma_f32_16x16x32_bf16(fah[i], fbl[j], acc[i][j], 0, 0, 0);
          acc[i][j] = __builtin_amdgcn_mfma_f32_16x16x32_bf16(fal[i], fbh[j], acc[i][j], 0, 0, 0);
        }
    }
  }
  // fused combine epilogue
  const unsigned short* wh = Wh + z * MAT;
  const unsigned short* wl = Wl + z * MAT;
  const unsigned short* uh = Uh + z * MAT;
  const unsigned short* ul = Ul + z * MAT;
  const float* dz = dcl + (z << 10);
  const float* iz = isq + (z << 10);
  float* Sb = S + z * MAT;
  for (int i = 0; i < 2; ++i) {
    int m0 = r0 + wm + i * 16 + q * 4;
    float dm[4], im[4];
    for (int reg = 0; reg < 4; ++reg) {
      dm[reg] = dz[m0 + reg];
      im[reg] = iz[m0 + reg];
    }
    for (int j = 0; j < 4; ++j) {
      int n = c0 + wn + j * 16 + ln;
      float dn = dz[n];
      float isn = iz[n];
      float sval[4];
      for (int reg = 0; reg < 4; ++reg) {
        size_t off = (size_t)(m0 + reg) * NN + n;
        float wv = bu2f(wh[off]) + bu2f(wl[off]);
        float uv = bu2f(uh[off]) + bu2f(ul[off]);
        float pf = 0.5f * (dm[reg] + dn) * im[reg] * isn;
        sval[reg] = pf * (wv + 0.8f * uv + 0.64f * acc[i][j][reg]);
        Sb[off] = sval[reg];
      }
      if ((n >> 6) > 2 * (m0 >> 7) + 1) {
        *(float4*)&Sb[(size_t)n * NN + m0] =
            make_float4(sval[0], sval[1], sval[2], sval[3]);
      }
    }
  }
}

// thr[b] = min(diag) - mean(diag[:-1] - offdiag)
__global__ void __launch_bounds__(256) k_thr(const float* __restrict__ S,
                                             float* __restrict__ thr) {
  const int b = blockIdx.x;
  const float* Sb = S + (size_t)b * NN * NN;
  const int tid = threadIdx.x;
  float mn = 3.0e38f;
  float rsum = 0.f;
  for (int n = tid; n < NN; n += 256) {
    float d = Sb[(size_t)n * NN + n];
    mn = fminf(mn, d);
    if (n < NN - 1) rsum += d - Sb[(size_t)n * NN + n + 1];
  }
  __shared__ float tmp[4];
  float mtot = blockMinF(mn, tmp);
  float stot = blockSumF(rsum, tmp);
  if (tid == 0) thr[b] = mtot - stot / 1023.0f;
}

// Fused stats + out: one block per n (1024 threads; thread owns column m=tid
// across all 8 batches, values in registers). One read of S instead of two.
__global__ void __launch_bounds__(1024) k_so(const float* __restrict__ S,
                                             const float* __restrict__ thr,
                                             const float* __restrict__ wh1,
                                             const float* __restrict__ wh2,
                                             const float* __restrict__ flag,
                                             void* outv) {
  const int n = blockIdx.x;
  const int tid = threadIdx.x;
  const int wid = tid >> 6;
  const bool f32m = (flag[0] != 0.0f);
  __shared__ double dred[32];
  __shared__ float fred[16];
  __shared__ float sres[2];
  float sv8[8], e8[8], t8[8];
  for (int b = 0; b < 8; ++b) {
    sv8[b] = S[((size_t)(b << 10) + n) * NN + tid];
    float e = wh1[(b << 10) + n] + wh2[(b << 10) + tid];
    e8[b] = (e > 0.f) ? e : 0.01f * e;
    t8[b] = thr[b];
  }
  double s1 = 0.0, s2 = 0.0;
  for (int b = 0; b < 8; ++b) {
    float att = (sv8[b] > t8[b]) ? e8[b] : NEGV;
    s1 += (double)att;
    s2 += (double)att * (double)att;
  }
  for (int d = 32; d; d >>= 1) {
    s1 += __shfl_down(s1, d);
    s2 += __shfl_down(s2, d);
  }
  if ((tid & 63) == 0) {
    dred[wid] = s1;
    dred[16 + wid] = s2;
  }
  __syncthreads();
  if (tid == 0) {
    double a = 0.0, c = 0.0;
    for (int w = 0; w < 16; ++w) { a += dred[w]; c += dred[16 + w]; }
    double mean = a / 8192.0;
    double var = c / 8192.0 - mean * mean;
    if (var < 0.0) var = 0.0;
    sres[0] = (float)mean;
    sres[1] = (float)(1.0 / sqrt(var + 1e-5));
  }
  __syncthreads();
  const float mean = sres[0], rstd = sres[1];
  for (int b = 0; b < 8; ++b) {
    float att = (sv8[b] > t8[b]) ? e8[b] : NEGV;
    float vv = (att - mean) * rstd;
    float mx = vv;
    for (int d = 32; d; d >>= 1) mx = fmaxf(mx, __shfl_down(mx, d));
    if ((tid & 63) == 0) fred[wid] = mx;
    __syncthreads();
    float gmx = fred[0];
    for (int w = 1; w < 16; ++w) gmx = fmaxf(gmx, fred[w]);
    float ex = __expf(vv - gmx);
    float sv = ex;
    for (int d = 32; d; d >>= 1) sv += __shfl_down(sv, d);
    __syncthreads();
    if ((tid & 63) == 0) fred[wid] = sv;
    __syncthreads();
    float gs = fred[0];
    for (int w = 1; w < 16; ++w) gs += fred[w];
    float val = ex / gs;
    if (f32m) {
      ((float*)outv)[((size_t)(b << 10) + n) * NN + tid] = val;
    } else {
      ((bf16*)outv)[((size_t)(b << 10) + n) * NN + tid] = __float2bfloat16(val);
    }
    __syncthreads();
  }
}

extern "C" void kernel_launch(void* const* d_in, const int* in_sizes, int n_in,
                              void* d_out, int out_size, void* d_ws,
                              size_t ws_size, hipStream_t stream) {
  float* ws = (float*)d_ws;

  float* sq = ws;              // 8192
  float* wh1 = ws + 8192;      // 8192
  float* wh2 = ws + 16384;     // 8192
  float* thr = ws + 24576;     // 8
  float* flag = ws + 26656;    // 8
  float* isq = ws + 26664;     // 8192
  float* rsum = ws + 40960;    // 8192
  float* dcl = ws + 49152;     // 8192

  unsigned short* Hh = (unsigned short*)(ws + 65536);   // 524288 ushorts
  unsigned short* Hl = (unsigned short*)(ws + 327680);  // 524288 ushorts

  unsigned short* Wh = (unsigned short*)(ws + 589824);
  unsigned short* Wl = (unsigned short*)(ws + 4784128);
  unsigned short* Uh = (unsigned short*)(ws + 17367040);
  unsigned short* Ul = (unsigned short*)(ws + 21561344);
  float* Sf = ws + 25755648;  // 8388608 floats (final S)
  const size_t needed_fast = (25755648ull + 8388608ull) * 4ull;

  if (ws_size < needed_fast) {
    k_fill<<<dim3(2048), 256, 0, stream>>>((unsigned short*)d_out, out_size,
                                           (unsigned short)0xBF80);
    return;
  }

  k_detect<<<dim3(1), 256, 0, stream>>>((const unsigned short*)d_in[0], flag);
  k_h<<<dim3(BB * NN), 64, 0, stream>>>(d_in[0], d_in[1], d_in[2], flag, Hh, Hl,
                                        sq, wh1, wh2);
  k_zero<<<dim3(32), 256, 0, stream>>>(rsum, BB * NN);
  k_g0<<<dim3(512), 256, 0, stream>>>(Hh, Hl, sq, rsum);
  k_scal<<<dim3(32), 256, 0, stream>>>(rsum, dcl, isq);
  k_gw<<<dim3(512), 256, 0, stream>>>(Hh, Hl, sq, isq, Wh, Wl);
  k_mm1<<<dim3(576), 256, 0, stream>>>(Wh, Wl, Uh, Ul);
  k_mm2<<<dim3(576), 256, 0, stream>>>(Uh, Ul, Wh, Wl, dcl, isq, Sf);
  k_thr<<<dim3(BB), 256, 0, stream>>>(Sf, thr);
  k_so<<<dim3(NN), 1024, 0, stream>>>(Sf, thr, wh1, wh2, flag, d_out);
}